// Round 4
// baseline (4275.249 us; speedup 1.0000x reference)
//
#include <hip/hip_runtime.h>
#if __has_include(<hip/hip_fp8.h>)
#include <hip/hip_fp8.h>
#define HAVE_HIP_FP8 1
#endif

typedef _Float16 f16;
typedef _Float16 f16x2 __attribute__((ext_vector_type(2)));
typedef _Float16 f16x4 __attribute__((ext_vector_type(4)));
typedef _Float16 f16x8 __attribute__((ext_vector_type(8)));
typedef float f32x4 __attribute__((ext_vector_type(4)));

#define S_LEN 1024
#define BATCH 32
#define HID 256
#define L2E 1.4426950408889634f
#define L2E2 2.8853900817779268f

#if __has_builtin(__builtin_amdgcn_fdot2)
#define FDOT2(a, b, c) __builtin_amdgcn_fdot2((a), (b), (c), false)
#else
static __device__ __forceinline__ float FDOT2(f16x2 a, f16x2 b, float c) {
  return c + (float)a[0] * (float)b[0] + (float)a[1] * (float)b[1];
}
#endif

__device__ __forceinline__ float EXP2(float x) {
#if __has_builtin(__builtin_amdgcn_exp2f)
  return __builtin_amdgcn_exp2f(x);
#else
  return exp2f(x);
#endif
}
__device__ __forceinline__ float RCP(float x) {
#if __has_builtin(__builtin_amdgcn_rcpf)
  return __builtin_amdgcn_rcpf(x);
#else
  return 1.0f / x;
#endif
}

__device__ __forceinline__ int PK_FP8(float a, float b) {
#if __has_builtin(__builtin_amdgcn_cvt_pk_fp8_f32)
  return __builtin_amdgcn_cvt_pk_fp8_f32(a, b, 0, false);
#elif defined(HAVE_HIP_FP8)
  __hip_fp8_e4m3 fa(a), fb(b);
  return (int)fa.__x | ((int)fb.__x << 8);
#else
#error "no fp8 conversion path on this target"
#endif
}

__device__ __forceinline__ float dot8(f16x8 w, f16x8 h, float acc) {
  f16x2 a, b;
  a[0] = w[0]; a[1] = w[1]; b[0] = h[0]; b[1] = h[1]; acc = FDOT2(a, b, acc);
  a[0] = w[2]; a[1] = w[3]; b[0] = h[2]; b[1] = h[3]; acc = FDOT2(a, b, acc);
  a[0] = w[4]; a[1] = w[5]; b[0] = h[4]; b[1] = h[5]; acc = FDOT2(a, b, acc);
  a[0] = w[6]; a[1] = w[7]; b[0] = h[6]; b[1] = h[7]; acc = FDOT2(a, b, acc);
  return acc;
}

// ---------------- wtag/wbin f32 -> f16 with per-256-block column permute ----------------
// dst[n][c'] = src[n][perm(c')], perm: c'=blk*256 + w*32 + 2*lr + p <- c = blk*256 + w*32 + p*16 + lr
__global__ void cvt_wperm(const float* __restrict__ src, f16* __restrict__ dst, int ncols, int total) {
  int idx = blockIdx.x * 256 + threadIdx.x;
  if (idx < total) {
    int n = idx / ncols, cp = idx % ncols;
    int blk = cp >> 8, cc = cp & 255;
    int w = cc >> 5, rem = cc & 31, lr = rem >> 1, p = rem & 1;
    int c = (blk << 8) + w * 32 + p * 16 + lr;
    dst[idx] = (f16)src[n * ncols + c];
  }
}

// ---------------- whh f32 -> fp8 e4m3, log2e-scaled, k-permuted ----------------
// dst[n][k'] = fp8(src[n][perm(k')] * sc),  k' = w*32 + 2*lr + p <-> k = w*32 + p*16 + lr
__global__ void cvt_whh_fp8(const float* __restrict__ src, unsigned char* __restrict__ dst) {
  int i = blockIdx.x * 256 + threadIdx.x;  // pair index: 1024 rows x 128 pairs
  if (i < 131072) {
    int n = i >> 7;
    int dp = i & 127;  // d' = k'>>1
    int w = dp >> 4, lr = dp & 15;
    float sc = (n >= 512 && n < 768) ? L2E2 : L2E;
    const float* r = src + (size_t)n * 256 + w * 32 + lr;
    float a = r[0] * sc, b = r[16] * sc;
    int pk = PK_FP8(a, b);
    *(short*)(dst + (size_t)n * 256 + dp * 2) = (short)(pk & 0xffff);
  }
}

// ---------------- input-projection GEMM -> fragment-major P ----------------
// P element for (t, b, n): q=b>>4, brow=b&15, lk=brow>>2, r=brow&3, lr=n&15,
// w=(n>>5)&7, nt=((n>>8)<<1)|((n>>4)&1), i=nt*4+r, tid=w*64+lk*16+lr
// offset = ((t*2+q)*512 + tid)*32 + i
__global__ __launch_bounds__(256) void proj_gemm(const float* __restrict__ A,
                                                 const float* __restrict__ W,
                                                 const float* __restrict__ bih,
                                                 const float* __restrict__ bhh,
                                                 f16* __restrict__ P, int K) {
  __shared__ f16 As[128 * 64];
  __shared__ f16 Bs[128 * 64];
  const int tid = threadIdx.x;
  const int bn = blockIdx.x;   // 0..7
  const int bm = blockIdx.y;   // 0..255
  const int lane = tid & 63, wid = tid >> 6;
  const int wm = wid >> 1, wn = wid & 1;
  const int lr = lane & 15, lk = lane >> 4;

  f32x4 acc[4][4];
#pragma unroll
  for (int i = 0; i < 4; ++i)
#pragma unroll
    for (int j = 0; j < 4; ++j) acc[i][j] = (f32x4){0.f, 0.f, 0.f, 0.f};

  for (int k0 = 0; k0 < K; k0 += 64) {
#pragma unroll
    for (int s = 0; s < 4; ++s) {
      int slot = s * 256 + tid;
      int row = slot >> 3, seg = slot & 7;
      {
        const float* ga = A + (size_t)(bm * 128 + row) * K + (k0 + seg * 8);
        float4 v0 = *(const float4*)ga;
        float4 v1 = *(const float4*)(ga + 4);
        f16x8 h;
        h[0] = (f16)v0.x; h[1] = (f16)v0.y; h[2] = (f16)v0.z; h[3] = (f16)v0.w;
        h[4] = (f16)v1.x; h[5] = (f16)v1.y; h[6] = (f16)v1.z; h[7] = (f16)v1.w;
        *(f16x8*)(&As[slot * 8]) = h;
      }
      {
        int ng = bn * 128 + row;
        float sc = (ng >= 512 && ng < 768) ? L2E2 : L2E;
        const float* gb = W + (size_t)ng * K + (k0 + seg * 8);
        float4 v0 = *(const float4*)gb;
        float4 v1 = *(const float4*)(gb + 4);
        f16x8 h;
        h[0] = (f16)(v0.x * sc); h[1] = (f16)(v0.y * sc); h[2] = (f16)(v0.z * sc); h[3] = (f16)(v0.w * sc);
        h[4] = (f16)(v1.x * sc); h[5] = (f16)(v1.y * sc); h[6] = (f16)(v1.z * sc); h[7] = (f16)(v1.w * sc);
        *(f16x8*)(&Bs[slot * 8]) = h;
      }
    }
    __syncthreads();
#pragma unroll
    for (int kk = 0; kk < 64; kk += 32) {
      f16x8 af[4], bf[4];
#pragma unroll
      for (int mi = 0; mi < 4; ++mi)
        af[mi] = *(const f16x8*)(&As[(wm * 64 + mi * 16 + lr) * 64 + kk + lk * 8]);
#pragma unroll
      for (int ni = 0; ni < 4; ++ni)
        bf[ni] = *(const f16x8*)(&Bs[(wn * 64 + ni * 16 + lr) * 64 + kk + lk * 8]);
#pragma unroll
      for (int mi = 0; mi < 4; ++mi)
#pragma unroll
        for (int ni = 0; ni < 4; ++ni)
          acc[mi][ni] = __builtin_amdgcn_mfma_f32_16x16x32_f16(af[mi], bf[ni], acc[mi][ni], 0, 0, 0);
    }
    __syncthreads();
  }

#pragma unroll
  for (int ni = 0; ni < 4; ++ni) {
    int col = bn * 128 + wn * 64 + ni * 16 + lr;
    float sc = (col >= 512 && col < 768) ? L2E2 : L2E;
    float bias = (bih[col] + bhh[col]) * sc;
    int lr2 = col & 15, w2 = (col >> 5) & 7;
    int nt2 = ((col >> 8) << 1) | ((col >> 4) & 1);
#pragma unroll
    for (int mi = 0; mi < 4; ++mi) {
#pragma unroll
      for (int r = 0; r < 4; ++r) {
        int rowg = bm * 128 + wm * 64 + mi * 16 + lk * 4 + r;
        int t = rowg & 1023, bb = rowg >> 10;
        int q = bb >> 4, brow = bb & 15;
        int lk2 = brow >> 2, r2 = brow & 3;
        int tid2 = w2 * 64 + lk2 * 16 + lr2;
        P[((size_t)(t * 2 + q) * 512 + tid2) * 32 + (nt2 * 4 + r2)] = (f16)(acc[mi][ni][r] + bias);
      }
    }
  }
}

// ---------------- LSTM recurrence: 8 WGs = (unit, batch-half), fp8 MFMA, weights in VGPRs ----------------
__global__ __attribute__((amdgpu_flat_work_group_size(512, 512), amdgpu_waves_per_eu(2, 2)))
void lstm_rec2(const unsigned char* __restrict__ whh8,
               const f16* __restrict__ Pall,
               const float* __restrict__ h0m,
               const float* __restrict__ c0m,
               const float* __restrict__ h0b,
               const float* __restrict__ c0b,
               f16* __restrict__ hid4) {
  const int wg = blockIdx.x;
  const int u = wg >> 1, q = wg & 1;
  const int dir = u & 1;
  const int tid = threadIdx.x;
  const int l = tid & 63, w = tid >> 6;
  const int lr = l & 15, lk = l >> 4;
  const int xr = (lr & 7) << 3;  // read-side swizzle (A row = lr)

  __shared__ __align__(16) char hbuf[2][4096];  // [16 rows][256 k'] fp8, XOR-swizzled

  // ---- load B-fragments (weights, fp8, k-permuted) into registers: 64 x 8B = 128 VGPR ----
  long long Bf[8][8];  // [ks][nt]
  const unsigned char* wbase = whh8 + ((size_t)u << 18);
#pragma unroll
  for (int nt = 0; nt < 8; ++nt) {
    int n = w * 32 + ((nt & 1) << 4) + lr + ((nt >> 1) << 8);
#pragma unroll
    for (int ks = 0; ks < 8; ++ks)
      Bf[ks][nt] = *(const long long*)(wbase + (size_t)n * 256 + ks * 32 + lk * 8);
  }

  // ---- init c state and h0 into hbuf[0] (short-packed, k'-layout) ----
  const float* h0 = (u < 2 ? h0m : h0b) + (size_t)dir * BATCH * HID;
  const float* c0 = (u < 2 ? c0m : c0b) + (size_t)dir * BATCH * HID;
  float cst[8];
#pragma unroll
  for (int r = 0; r < 4; ++r) {
    int brow = lk * 4 + r;
    int bglob = q * 16 + brow;
    int wxr = (brow & 7) << 3;
    int j0 = w * 32 + lr;
    cst[r * 2 + 0] = c0[bglob * HID + j0];
    cst[r * 2 + 1] = c0[bglob * HID + j0 + 16];
    float hv0 = h0[bglob * HID + j0];
    float hv1 = h0[bglob * HID + j0 + 16];
    int pk = PK_FP8(hv0, hv1);
    *(short*)(&hbuf[0][brow * 256 + ((w * 32 + 2 * lr) ^ wxr)]) = (short)(pk & 0xffff);
  }

  // ---- preload P for s=0 (fragment-major: one 64B run per thread) ----
  const f16* Pu = Pall + ((size_t)u << 25);
  const f16* ptbase = Pu + ((size_t)q * 512 + tid) * 32;
  f16x8 PA[4], PB[4];
  {
    int t0 = dir ? (S_LEN - 1) : 0;
    const f16x8* p8 = (const f16x8*)(ptbase + (size_t)t0 * 32768);
#pragma unroll
    for (int k = 0; k < 4; ++k) PA[k] = p8[k];
  }
  __syncthreads();

#define LSTM_BODY(S_, SP_, PC_, PN_)                                                       \
  {                                                                                        \
    const int t = dir ? (S_LEN - 1 - (S_)) : (S_);                                         \
    {                                                                                      \
      int s2 = ((S_) + 1 < S_LEN) ? (S_) + 1 : (S_);                                       \
      int t2 = dir ? (S_LEN - 1 - s2) : s2;                                                \
      const f16x8* p8 = (const f16x8*)(ptbase + (size_t)t2 * 32768);                       \
      _Pragma("unroll") for (int k = 0; k < 4; ++k) PN_[k] = p8[k];                        \
    }                                                                                      \
    f32x4 acc[8];                                                                          \
    _Pragma("unroll") for (int nt = 0; nt < 8; ++nt)                                       \
        _Pragma("unroll") for (int r = 0; r < 4; ++r)                                      \
            acc[nt][r] = (float)PC_[(nt * 4 + r) >> 3][(nt * 4 + r) & 7];                  \
    const char* hb_rd = &hbuf[SP_][lr * 256];                                              \
    _Pragma("unroll") for (int ks = 0; ks < 8; ++ks) {                                     \
      long long Afk = *(const long long*)(hb_rd + ((ks * 32 + lk * 8) ^ xr));              \
      _Pragma("unroll") for (int nt = 0; nt < 8; ++nt)                                     \
          acc[nt] = __builtin_amdgcn_mfma_f32_16x16x32_fp8_fp8(Afk, Bf[ks][nt], acc[nt], 0, 0, 0); \
    }                                                                                      \
    _Pragma("unroll") for (int r = 0; r < 4; ++r) {                                        \
      int brow = lk * 4 + r;                                                               \
      int wxr = (brow & 7) << 3;                                                           \
      float h_[2];                                                                         \
      _Pragma("unroll") for (int jj = 0; jj < 2; ++jj) {                                   \
        float zi = acc[0 + jj][r], zf = acc[2 + jj][r], zg = acc[4 + jj][r], zo = acc[6 + jj][r]; \
        float ei = EXP2(-zi), ef = EXP2(-zf), eg = EXP2(-zg), eo = EXP2(-zo);              \
        float di = 1.f + ei, df = 1.f + ef, dg = 1.f + eg, dof = 1.f + eo;                 \
        float r1 = RCP(di * df);                                                           \
        float si = r1 * df, sf = r1 * di;                                                  \
        float r2 = RCP(dg * dof);                                                          \
        float tg = 2.f * (r2 * dof) - 1.f, so = r2 * dg;                                   \
        float c = sf * cst[r * 2 + jj] + si * tg;                                          \
        cst[r * 2 + jj] = c;                                                               \
        float ec = EXP2(-L2E2 * c);                                                        \
        float th = 2.f * RCP(1.f + ec) - 1.f;                                              \
        h_[jj] = so * th;                                                                  \
      }                                                                                    \
      int pk = PK_FP8(h_[0], h_[1]);                                                       \
      *(short*)(&hbuf[SP_ ^ 1][brow * 256 + ((w * 32 + 2 * lr) ^ wxr)]) = (short)(pk & 0xffff); \
      f16x2 hp;                                                                            \
      hp[0] = (f16)h_[0]; hp[1] = (f16)h_[1];                                              \
      *(f16x2*)(&hid4[((size_t)(q * 16 + brow) << 20) + ((size_t)t << 10) + u * 256 + w * 32 + 2 * lr]) = hp; \
    }                                                                                      \
    __syncthreads();                                                                       \
  }

  for (int s = 0; s < S_LEN; s += 2) {
    LSTM_BODY(s, 0, PA, PB);
    LSTM_BODY(s + 1, 1, PB, PA);
  }
#undef LSTM_BODY
}

// ---------------- emissions (hid4 and wtag/wbin share the permuted column order) ----------------
__global__ __launch_bounds__(256) void emis_kernel(const f16* __restrict__ hid4,
                                                   const f16* __restrict__ wtag,
                                                   const float* __restrict__ btag,
                                                   const f16* __restrict__ wbin,
                                                   const float* __restrict__ bbin,
                                                   float* __restrict__ emis,
                                                   float* __restrict__ emisb) {
  const int tid = threadIdx.x;
  const int rl = tid >> 4, n = tid & 15;
  const size_t row = (size_t)blockIdx.x * 16 + rl;
  const f16x8* hv = (const f16x8*)(hid4 + row * 1024);
  const f16x8* wv = (const f16x8*)(wtag + n * 1024);
  float acc = btag[n];
#pragma unroll 8
  for (int kc = 0; kc < 128; ++kc) acc = dot8(wv[kc], hv[kc], acc);
  emis[row * 16 + n] = acc;
  if (n < 5) {
    const f16x8* hv2 = (const f16x8*)(hid4 + row * 1024 + 512);
    const f16x8* wv2 = (const f16x8*)(wbin + (size_t)n * 512);
    float a2 = bbin[n];
#pragma unroll 8
    for (int kc = 0; kc < 64; ++kc) a2 = dot8(wv2[kc], hv2[kc], a2);
    emisb[row * 5 + n] = a2;
  }
}

// ---------------- CRF forward (logZ) — round-1 proven version ----------------
__global__ __launch_bounds__(64) void crf_logz(const float* __restrict__ emis,
                                               const float* __restrict__ trans,
                                               const float* __restrict__ emisb,
                                               const float* __restrict__ transb,
                                               const float* __restrict__ mask,
                                               float* __restrict__ outLogZ) {
  const int crf = blockIdx.x >> 5, b = blockIdx.x & 31;
  const int NTc = crf ? 5 : 16;
  const float* __restrict__ E = crf ? emisb : emis;
  const float* __restrict__ T = crf ? transb : trans;
  const int lane = threadIdx.x;
  const int j = lane >> 2, p = lane & 3;
  const bool jv = (j < NTc);
  float Tc[4];
#pragma unroll
  for (int ii = 0; ii < 4; ++ii) {
    int i = p * 4 + ii;
    Tc[ii] = (jv && i < NTc) ? T[i * NTc + j] : -1e30f;
  }
  __shared__ float as_[16];
  if (lane < 16) as_[lane] = -1e30f;
  float alpha = 0.f;
  __syncthreads();
  if (jv && p == 0) {
    alpha = T[1 * NTc + j] + E[(size_t)(b << 10) * NTc + j];  // SOS=1, t=0
    as_[j] = alpha;
  }
  __syncthreads();
  for (int t = 1; t < S_LEN; ++t) {
    float m_t = mask[(b << 10) + t];
    float v[4];
#pragma unroll
    for (int ii = 0; ii < 4; ++ii) {
      int i = p * 4 + ii;
      v[ii] = (jv && i < NTc) ? (as_[i] + Tc[ii]) : -1e30f;
    }
    float mx = fmaxf(fmaxf(v[0], v[1]), fmaxf(v[2], v[3]));
    mx = fmaxf(mx, __shfl_xor(mx, 1, 4));
    mx = fmaxf(mx, __shfl_xor(mx, 2, 4));
    float ssum = __expf(v[0] - mx) + __expf(v[1] - mx) + __expf(v[2] - mx) + __expf(v[3] - mx);
    ssum += __shfl_xor(ssum, 1, 4);
    ssum += __shfl_xor(ssum, 2, 4);
    if (jv && p == 0) {
      float e_tj = E[((size_t)(b << 10) + t) * NTc + j];
      float newv = e_tj + mx + __logf(ssum);
      alpha = (m_t > 0.5f) ? newv : alpha;
    }
    __syncthreads();
    if (jv && p == 0) as_[j] = alpha;
    __syncthreads();
  }
  if (lane == 0) {
    float mx = -1e30f;
    for (int jj = 0; jj < NTc; ++jj) mx = fmaxf(mx, as_[jj] + T[jj * NTc + 2]);  // EOS=2
    float ssum = 0.f;
    for (int jj = 0; jj < NTc; ++jj) ssum += __expf(as_[jj] + T[jj * NTc + 2] - mx);
    outLogZ[crf * 32 + b] = mx + __logf(ssum);
  }
}

// ---------------- CRF gold score ----------------
__global__ __launch_bounds__(64) void crf_score(const float* __restrict__ emis,
                                                const float* __restrict__ trans,
                                                const float* __restrict__ emisb,
                                                const float* __restrict__ transb,
                                                const float* __restrict__ mask,
                                                const int* __restrict__ tags,
                                                const int* __restrict__ tagsb,
                                                float* __restrict__ outScore) {
  const int crf = blockIdx.x >> 5, b = blockIdx.x & 31;
  const int NTc = crf ? 5 : 16;
  const float* __restrict__ E = crf ? emisb : emis;
  const float* __restrict__ T = crf ? transb : trans;
  const int* __restrict__ tg = (crf ? tagsb : tags) + (b << 10);
  const float* __restrict__ mk = mask + (b << 10);
  const int lane = threadIdx.x;
  float s = 0.f, cnt = 0.f;
  for (int t = lane; t < S_LEN; t += 64) {
    float m = mk[t];
    cnt += m;
    if (t >= 1 && m > 0.5f)
      s += E[((size_t)(b << 10) + t) * NTc + tg[t]] + T[tg[t - 1] * NTc + tg[t]];
  }
#pragma unroll
  for (int off = 32; off >= 1; off >>= 1) {
    s += __shfl_down(s, off);
    cnt += __shfl_down(cnt, off);
  }
  if (lane == 0) {
    int L = (int)(cnt + 0.5f);
    int t0 = tg[0];
    float tot = T[1 * NTc + t0] + E[(size_t)(b << 10) * NTc + t0] + s + T[tg[L - 1] * NTc + 2];
    outScore[crf * 32 + b] = tot;
  }
}

__global__ void finalk(const float* __restrict__ logZ, const float* __restrict__ score,
                       float* __restrict__ out) {
  int j = threadIdx.x;
  if (j < 2) {
    float a = 0.f;
    for (int b = 0; b < 32; ++b) a += logZ[j * 32 + b] - score[j * 32 + b];
    out[j] = a;
  }
}

extern "C" void kernel_launch(void* const* d_in, const int* in_sizes, int n_in,
                              void* d_out, int out_size, void* d_ws, size_t ws_size,
                              hipStream_t stream) {
  const float* x       = (const float*)d_in[0];
  const float* xbin    = (const float*)d_in[1];
  const float* mask    = (const float*)d_in[2];
  const int*   tags    = (const int*)d_in[3];
  const int*   tagsb   = (const int*)d_in[4];
  const float* trans   = (const float*)d_in[5];
  const float* transb  = (const float*)d_in[6];
  const float* w2f_ih  = (const float*)d_in[7];
  const float* w2f_hh  = (const float*)d_in[8];
  const float* b2f_ih  = (const float*)d_in[9];
  const float* b2f_hh  = (const float*)d_in[10];
  const float* w2b_ih  = (const float*)d_in[11];
  const float* w2b_hh  = (const float*)d_in[12];
  const float* b2b_ih  = (const float*)d_in[13];
  const float* b2b_hh  = (const float*)d_in[14];
  const float* w_bin   = (const float*)d_in[15];
  const float* bb_bin  = (const float*)d_in[16];
  const float* w1f_ih  = (const float*)d_in[17];
  const float* w1f_hh  = (const float*)d_in[18];
  const float* b1f_ih  = (const float*)d_in[19];
  const float* b1f_hh  = (const float*)d_in[20];
  const float* w1b_ih  = (const float*)d_in[21];
  const float* w1b_hh  = (const float*)d_in[22];
  const float* b1b_ih  = (const float*)d_in[23];
  const float* b1b_hh  = (const float*)d_in[24];
  const float* w_tag   = (const float*)d_in[25];
  const float* b_tag   = (const float*)d_in[26];
  const float* h0_bin  = (const float*)d_in[27];
  const float* c0_bin  = (const float*)d_in[28];
  const float* h0_main = (const float*)d_in[29];
  const float* c0_main = (const float*)d_in[30];

  char* ws = (char*)d_ws;
  f16* P      = (f16*)(ws);                          // 4 x 33554432 f16 = 256 MiB
  f16* hid4   = (f16*)(ws + 268435456);              // 64 MiB
  unsigned char* whh8 = (unsigned char*)(ws + 335544320);  // 4 x 262144 B = 1 MiB
  f16* wtag   = (f16*)(ws + 336592896);              // 16384 f16
  f16* wbin   = (f16*)(ws + 336625664);              // 2560 f16
  float* emis  = (float*)(ws + 336630784);           // 32768*16 f32
  float* emisb = (float*)(ws + 338727936);           // 32768*5 f32
  float* logZ  = (float*)(ws + 339383296);           // 64 f32
  float* score = (float*)(ws + 339383552);           // 64 f32

  // weight preps (k'-permuted)
  cvt_whh_fp8<<<512, 256, 0, stream>>>(w1f_hh, whh8 + 0 * 262144);
  cvt_whh_fp8<<<512, 256, 0, stream>>>(w1b_hh, whh8 + 1 * 262144);
  cvt_whh_fp8<<<512, 256, 0, stream>>>(w2f_hh, whh8 + 2 * 262144);
  cvt_whh_fp8<<<512, 256, 0, stream>>>(w2b_hh, whh8 + 3 * 262144);
  cvt_wperm<<<64, 256, 0, stream>>>(w_tag, wtag, 1024, 16384);
  cvt_wperm<<<10, 256, 0, stream>>>(w_bin, wbin, 512, 2560);

  // input projections (log2e-scaled, fragment-major P): units 0..3 = main_f, main_b, bin_f, bin_b
  dim3 gg(8, 256);
  proj_gemm<<<gg, 256, 0, stream>>>(x, w1f_ih, b1f_ih, b1f_hh, P + (size_t)0 * 33554432, 512);
  proj_gemm<<<gg, 256, 0, stream>>>(x, w1b_ih, b1b_ih, b1b_hh, P + (size_t)1 * 33554432, 512);
  proj_gemm<<<gg, 256, 0, stream>>>(xbin, w2f_ih, b2f_ih, b2f_hh, P + (size_t)2 * 33554432, 1536);
  proj_gemm<<<gg, 256, 0, stream>>>(xbin, w2b_ih, b2b_ih, b2b_hh, P + (size_t)3 * 33554432, 1536);

  lstm_rec2<<<8, 512, 0, stream>>>(whh8, P, h0_main, c0_main, h0_bin, c0_bin, hid4);
  emis_kernel<<<2048, 256, 0, stream>>>(hid4, wtag, b_tag, wbin, bb_bin, emis, emisb);
  crf_logz<<<64, 64, 0, stream>>>(emis, trans, emisb, transb, mask, logZ);
  crf_score<<<64, 64, 0, stream>>>(emis, trans, emisb, transb, mask, tags, tagsb, score);
  finalk<<<1, 64, 0, stream>>>(logZ, score, (float*)d_out);
}

// Round 5
// 2978.453 us; speedup vs baseline: 1.4354x; 1.4354x over previous
//
#include <hip/hip_runtime.h>

typedef _Float16 f16;
typedef _Float16 f16x2 __attribute__((ext_vector_type(2)));
typedef _Float16 f16x4 __attribute__((ext_vector_type(4)));
typedef _Float16 f16x8 __attribute__((ext_vector_type(8)));
typedef float f32x4 __attribute__((ext_vector_type(4)));
typedef int iv4 __attribute__((ext_vector_type(4)));

#define S_LEN 1024
#define BATCH 32
#define HID 256
#define L2E 1.4426950408889634f
#define L2E2 2.8853900817779268f

#if __has_builtin(__builtin_amdgcn_fdot2)
#define FDOT2(a, b, c) __builtin_amdgcn_fdot2((a), (b), (c), false)
#else
static __device__ __forceinline__ float FDOT2(f16x2 a, f16x2 b, float c) {
  return c + (float)a[0] * (float)b[0] + (float)a[1] * (float)b[1];
}
#endif

__device__ __forceinline__ float EXP2(float x) {
#if __has_builtin(__builtin_amdgcn_exp2f)
  return __builtin_amdgcn_exp2f(x);
#else
  return exp2f(x);
#endif
}
__device__ __forceinline__ float RCP(float x) {
#if __has_builtin(__builtin_amdgcn_rcpf)
  return __builtin_amdgcn_rcpf(x);
#else
  return 1.0f / x;
#endif
}

// barrier that waits LDS only (no vmcnt drain of hid4 stores / P prefetch)
#define WG_BARRIER()                                                  \
  do {                                                                \
    __builtin_amdgcn_sched_barrier(0);                                \
    asm volatile("s_waitcnt lgkmcnt(0)\n\ts_barrier" ::: "memory");   \
    __builtin_amdgcn_sched_barrier(0);                                \
  } while (0)

__device__ __forceinline__ float dot8(f16x8 w, f16x8 h, float acc) {
  f16x2 a, b;
  a[0] = w[0]; a[1] = w[1]; b[0] = h[0]; b[1] = h[1]; acc = FDOT2(a, b, acc);
  a[0] = w[2]; a[1] = w[3]; b[0] = h[2]; b[1] = h[3]; acc = FDOT2(a, b, acc);
  a[0] = w[4]; a[1] = w[5]; b[0] = h[4]; b[1] = h[5]; acc = FDOT2(a, b, acc);
  a[0] = w[6]; a[1] = w[7]; b[0] = h[6]; b[1] = h[7]; acc = FDOT2(a, b, acc);
  return acc;
}

// ---------------- f32 -> f16 convert (plain) ----------------
__global__ void cvt_f32_f16(const float* __restrict__ src, f16* __restrict__ dst, int n4) {
  int i = blockIdx.x * 256 + threadIdx.x;
  if (i < n4) {
    float4 v = ((const float4*)src)[i];
    f16x4 h;
    h[0] = (f16)v.x; h[1] = (f16)v.y; h[2] = (f16)v.z; h[3] = (f16)v.w;
    ((f16x4*)dst)[i] = h;
  }
}

// ---------------- whh f32 -> i8 per-row symmetric quant, log2e pre-scaled ----------------
// one wave per row (256 k). Wq[n][k] linear; fsc[n] = rowmax/16129 (z = P + fsc*iacc).
__global__ __launch_bounds__(256) void quant_whh(const float* __restrict__ src,
                                                 char* __restrict__ dstq,
                                                 float* __restrict__ fsc) {
  const int row = blockIdx.x * 4 + (threadIdx.x >> 6);
  const int lane = threadIdx.x & 63;
  const float sc = (row >= 512 && row < 768) ? L2E2 : L2E;
  float4 v = *(const float4*)(src + (size_t)row * 256 + lane * 4);
  float w0 = v.x * sc, w1 = v.y * sc, w2 = v.z * sc, w3 = v.w * sc;
  float mx = fmaxf(fmaxf(fabsf(w0), fabsf(w1)), fmaxf(fabsf(w2), fabsf(w3)));
#pragma unroll
  for (int off = 1; off < 64; off <<= 1) mx = fmaxf(mx, __shfl_xor(mx, off));
  mx = fmaxf(mx, 1e-20f);
  float inv = 127.0f / mx;
  int q0 = (int)rintf(w0 * inv), q1 = (int)rintf(w1 * inv);
  int q2 = (int)rintf(w2 * inv), q3 = (int)rintf(w3 * inv);
  int pk = (q0 & 0xff) | ((q1 & 0xff) << 8) | ((q2 & 0xff) << 16) | ((q3 & 0xff) << 24);
  ((int*)(dstq + (size_t)row * 256))[lane] = pk;
  if (lane == 0) fsc[row] = mx / 16129.0f;
}

// ---------------- input-projection GEMM -> P4 planes ----------------
// grid (v 0..3, bm 0..255). Tile: 4 batches x 32 t x 256 cols, K-step 64.
// bm: bgrp=bm>>5 (b0=bgrp*4, c=bgrp>>1, lkb=bgrp&1), t0=(bm&31)*32.
// P4 dest (bytes): Pu + v*16MiB + (((t*4+c)*512 + w*64 + jj*32 + lkb*16 + lr) * 8),
// payload = f16x4 over r=0..3 (batch b0+r). Gate col n: v=n>>8, w=(n>>5)&7, jj=(n>>4)&1, lr=n&15.
__global__ __launch_bounds__(256) void proj_gemm(const float* __restrict__ A,
                                                 const float* __restrict__ W,
                                                 const float* __restrict__ bih,
                                                 const float* __restrict__ bhh,
                                                 char* __restrict__ Pu, int K) {
  __shared__ __align__(16) char smem[65536];
  f16* As = (f16*)smem;            // [128][64]
  f16* Bs = (f16*)(smem + 16384);  // [256][64]
  const int v = blockIdx.x;
  const int bm = blockIdx.y;
  const int bgrp = bm >> 5, t0 = (bm & 31) * 32;
  const int b0 = bgrp * 4, c = bgrp >> 1, lkb = bgrp & 1;
  const float sc = (v == 2) ? L2E2 : L2E;
  const int tid = threadIdx.x;
  const int lane = tid & 63, wid = tid >> 6;
  const int wm = wid >> 1, wn = wid & 1;
  const int lr = lane & 15, lk = lane >> 4;

  f32x4 acc[4][8];
#pragma unroll
  for (int i = 0; i < 4; ++i)
#pragma unroll
    for (int n = 0; n < 8; ++n) acc[i][n] = (f32x4){0.f, 0.f, 0.f, 0.f};

  for (int k0 = 0; k0 < K; k0 += 64) {
    // stage A: 128 rows x 8 segs = 1024 slots, 4/thread
#pragma unroll
    for (int s = 0; s < 4; ++s) {
      int slot = s * 256 + tid;
      int row = slot >> 3, seg = slot & 7;
      size_t arow = (size_t)(b0 + (row >> 5)) * 1024 + t0 + (row & 31);
      const float* ga = A + arow * K + (k0 + seg * 8);
      float4 v0 = *(const float4*)ga;
      float4 v1 = *(const float4*)(ga + 4);
      f16x8 h;
      h[0] = (f16)v0.x; h[1] = (f16)v0.y; h[2] = (f16)v0.z; h[3] = (f16)v0.w;
      h[4] = (f16)v1.x; h[5] = (f16)v1.y; h[6] = (f16)v1.z; h[7] = (f16)v1.w;
      *(f16x8*)(&As[slot * 8]) = h;
    }
    // stage B: 256 rows x 8 segs = 2048 slots, 8/thread
#pragma unroll
    for (int s = 0; s < 8; ++s) {
      int slot = s * 256 + tid;
      int row = slot >> 3, seg = slot & 7;
      const float* gb = W + (size_t)(v * 256 + row) * K + (k0 + seg * 8);
      float4 v0 = *(const float4*)gb;
      float4 v1 = *(const float4*)(gb + 4);
      f16x8 h;
      h[0] = (f16)(v0.x * sc); h[1] = (f16)(v0.y * sc); h[2] = (f16)(v0.z * sc); h[3] = (f16)(v0.w * sc);
      h[4] = (f16)(v1.x * sc); h[5] = (f16)(v1.y * sc); h[6] = (f16)(v1.z * sc); h[7] = (f16)(v1.w * sc);
      *(f16x8*)(&Bs[slot * 8]) = h;
    }
    __syncthreads();
#pragma unroll
    for (int kk = 0; kk < 64; kk += 32) {
      f16x8 af[4], bf[8];
#pragma unroll
      for (int mi = 0; mi < 4; ++mi)
        af[mi] = *(const f16x8*)(&As[(wm * 64 + mi * 16 + lr) * 64 + kk + lk * 8]);
#pragma unroll
      for (int ni = 0; ni < 8; ++ni)
        bf[ni] = *(const f16x8*)(&Bs[(wn * 128 + ni * 16 + lr) * 64 + kk + lk * 8]);
#pragma unroll
      for (int mi = 0; mi < 4; ++mi)
#pragma unroll
        for (int ni = 0; ni < 8; ++ni)
          acc[mi][ni] = __builtin_amdgcn_mfma_f32_16x16x32_f16(af[mi], bf[ni], acc[mi][ni], 0, 0, 0);
    }
    __syncthreads();
  }

  // epilogue: acc -> LDS2 (64KB, reuses smem) -> coalesced 8B stores
  float biasv[8];
#pragma unroll
  for (int ni = 0; ni < 8; ++ni) {
    int n = v * 256 + wn * 128 + ni * 16 + lr;
    biasv[ni] = (bih[n] + bhh[n]) * sc;
  }
#pragma unroll
  for (int mi = 0; mi < 4; ++mi) {
#pragma unroll
    for (int ni = 0; ni < 8; ++ni) {
      int col = wn * 128 + ni * 16 + lr;
      int wc = col >> 5, jc = (col >> 4) & 1, lc = col & 15;
#pragma unroll
      for (int rr = 0; rr < 4; ++rr) {
        int row = wm * 64 + mi * 16 + lk * 4 + rr;
        int bsub = row >> 5, t_loc = row & 31;
        int unit = t_loc * 256 + wc * 32 + jc * 16 + lc;
        int off = (unit * 8 + bsub * 2) ^ ((t_loc & 7) << 4);
        *(f16*)(smem + off) = (f16)(acc[mi][ni][rr] + biasv[ni]);
      }
    }
  }
  __syncthreads();
  char* Pv = Pu + ((size_t)v << 24);
#pragma unroll
  for (int k = 0; k < 32; ++k) {
    int uid = k * 256 + tid;
    int t_loc = uid >> 8, sub = uid & 255;
    int off = (uid * 8) ^ ((t_loc & 7) << 4);
    unsigned long long val = *(const unsigned long long*)(smem + off);
    int wq = sub >> 5, jq = (sub >> 4) & 1, lq = sub & 15;
    size_t didx = (((size_t)((t0 + t_loc) * 4 + c) * 512) + wq * 64 + jq * 32 + lkb * 16 + lq) << 3;
    *(unsigned long long*)(Pv + didx) = val;
  }
}

// ---------------- LSTM recurrence: 16 WGs = (unit, batch-quarter), i8 MFMA, weights in regs ----------------
__global__ __attribute__((amdgpu_flat_work_group_size(512, 512), amdgpu_waves_per_eu(2, 2)))
void lstm_rec3(const char* __restrict__ Wq4,
               const float* __restrict__ fsc4,
               const char* __restrict__ P4,
               const float* __restrict__ h0m,
               const float* __restrict__ c0m,
               const float* __restrict__ h0b,
               const float* __restrict__ c0b,
               f16* __restrict__ hid4) {
  const int wg = blockIdx.x;
  const int u = wg >> 2, c = wg & 3;
  const int dir = u & 1;
  const int tid = threadIdx.x;
  const int l = tid & 63, w = tid >> 6;
  const int lr = l & 15, lk = l >> 4;
  const int jj = lk >> 1, lkb = lk & 1;
  const int r8 = lr & 7;
  const int j = w * 32 + jj * 16 + lr;  // hidden unit owned by this (cell-)lane

  __shared__ __align__(16) char hbuf[2][2048];  // [8 batch rows][256 k] i8, XOR-swizzled

  // ---- weights: 32 x iv4 = 128 VGPR; n = v*256 + w*32 + (nt&1)*16 + lr ----
  iv4 Bf[4][8];
  const char* wb = Wq4 + ((size_t)u << 18);
#pragma unroll
  for (int nt = 0; nt < 8; ++nt) {
    int n = (nt >> 1) * 256 + w * 32 + ((nt & 1) << 4) + lr;
#pragma unroll
    for (int ks = 0; ks < 4; ++ks)
      Bf[ks][nt] = *(const iv4*)(wb + (size_t)n * 256 + ks * 64 + lk * 16);
  }
  float fv[4];
#pragma unroll
  for (int v = 0; v < 4; ++v) fv[v] = fsc4[u * 1024 + v * 256 + j];

  // ---- init c / h0 ----
  const float* h0 = (u < 2 ? h0m : h0b) + (size_t)dir * BATCH * HID;
  const float* c0 = (u < 2 ? c0m : c0b) + (size_t)dir * BATCH * HID;
  float cst[4];
#pragma unroll
  for (int r = 0; r < 4; ++r) {
    int brow = lkb * 4 + r;
    int b = c * 8 + brow;
    cst[r] = c0[b * HID + j];
    float hv = h0[b * HID + j];
    int hq = (int)rintf(hv * 127.f);
    hq = hq > 127 ? 127 : (hq < -127 ? -127 : hq);
    hbuf[0][brow * 256 + (j ^ (brow << 4))] = (char)hq;
  }

  // ---- P preload (4 planes x 8B) ----
  const char* Pc = P4 + ((size_t)u << 26);
  f16x4 Pa[4], Pb[4];
  {
    int t0 = dir ? (S_LEN - 1) : 0;
#pragma unroll
    for (int v = 0; v < 4; ++v)
      Pa[v] = *(const f16x4*)(Pc + ((size_t)v << 24) + ((((size_t)t0 * 4 + c) * 512 + tid) << 3));
  }
  WG_BARRIER();

#define LSTM_BODY(S_, SP_, PC_, PN_)                                                        \
  {                                                                                         \
    const int t = dir ? (S_LEN - 1 - (S_)) : (S_);                                          \
    {                                                                                       \
      int s2 = ((S_) + 1 < S_LEN) ? (S_) + 1 : (S_);                                        \
      int t2 = dir ? (S_LEN - 1 - s2) : s2;                                                 \
      _Pragma("unroll") for (int v = 0; v < 4; ++v)                                         \
          PN_[v] = *(const f16x4*)(Pc + ((size_t)v << 24) +                                 \
                                   ((((size_t)t2 * 4 + c) * 512 + tid) << 3));              \
    }                                                                                       \
    iv4 ia[8];                                                                              \
    _Pragma("unroll") for (int nt = 0; nt < 8; ++nt) ia[nt] = (iv4){0, 0, 0, 0};            \
    const char* hb = hbuf[SP_];                                                             \
    _Pragma("unroll") for (int ks = 0; ks < 4; ++ks) {                                      \
      iv4 Af = *(const iv4*)(hb + r8 * 256 + ((ks * 64 + lk * 16) ^ (r8 << 4)));            \
      _Pragma("unroll") for (int nt = 0; nt < 8; ++nt)                                      \
          ia[nt] = __builtin_amdgcn_mfma_i32_16x16x64_i8(Af, Bf[ks][nt], ia[nt], 0, 0, 0);  \
    }                                                                                       \
    float z[4][4];                                                                          \
    _Pragma("unroll") for (int v = 0; v < 4; ++v) {                                         \
      _Pragma("unroll") for (int r = 0; r < 4; ++r) {                                       \
        int sw = __shfl_xor(ia[v * 2 + 1][r], 32);                                          \
        int iaz = (l < 32) ? ia[v * 2][r] : sw;                                             \
        z[v][r] = (float)PC_[v][r] + fv[v] * (float)iaz;                                    \
      }                                                                                     \
    }                                                                                       \
    _Pragma("unroll") for (int r = 0; r < 4; ++r) {                                         \
      float zi = z[0][r], zf = z[1][r], zg = z[2][r], zo = z[3][r];                         \
      float ei = EXP2(-zi), ef = EXP2(-zf), eg = EXP2(-zg), eo = EXP2(-zo);                 \
      float di = 1.f + ei, df = 1.f + ef, dg = 1.f + eg, dof = 1.f + eo;                    \
      float r1 = RCP(di * df);                                                              \
      float si = r1 * df, sf = r1 * di;                                                     \
      float r2 = RCP(dg * dof);                                                             \
      float tg = 2.f * (r2 * dof) - 1.f, so = r2 * dg;                                      \
      float cc = sf * cst[r] + si * tg;                                                     \
      cst[r] = cc;                                                                          \
      float ec = EXP2(-L2E2 * cc);                                                          \
      float th = 2.f * RCP(1.f + ec) - 1.f;                                                 \
      float hh = so * th;                                                                   \
      int brow = lkb * 4 + r;                                                               \
      int hq = (int)rintf(hh * 127.f);                                                      \
      hbuf[SP_ ^ 1][brow * 256 + (j ^ (brow << 4))] = (char)hq;                             \
      int b = c * 8 + brow;                                                                 \
      hid4[((size_t)b << 20) + ((size_t)t << 10) + (u << 8) + j] = (f16)hh;                 \
    }                                                                                       \
    WG_BARRIER();                                                                           \
  }

  for (int s = 0; s < S_LEN; s += 2) {
    LSTM_BODY(s, 0, Pa, Pb);
    LSTM_BODY(s + 1, 1, Pb, Pa);
  }
#undef LSTM_BODY
}

// ---------------- emissions ----------------
__global__ __launch_bounds__(256) void emis_kernel(const f16* __restrict__ hid4,
                                                   const f16* __restrict__ wtag,
                                                   const float* __restrict__ btag,
                                                   const f16* __restrict__ wbin,
                                                   const float* __restrict__ bbin,
                                                   float* __restrict__ emis,
                                                   float* __restrict__ emisb) {
  const int tid = threadIdx.x;
  const int rl = tid >> 4, n = tid & 15;
  const size_t row = (size_t)blockIdx.x * 16 + rl;
  const f16x8* hv = (const f16x8*)(hid4 + row * 1024);
  const f16x8* wv = (const f16x8*)(wtag + n * 1024);
  float acc = btag[n];
#pragma unroll 8
  for (int kc = 0; kc < 128; ++kc) acc = dot8(wv[kc], hv[kc], acc);
  emis[row * 16 + n] = acc;
  if (n < 5) {
    const f16x8* hv2 = (const f16x8*)(hid4 + row * 1024 + 512);
    const f16x8* wv2 = (const f16x8*)(wbin + (size_t)n * 512);
    float a2 = bbin[n];
#pragma unroll 8
    for (int kc = 0; kc < 64; ++kc) a2 = dot8(wv2[kc], hv2[kc], a2);
    emisb[row * 5 + n] = a2;
  }
}

// ---------------- CRF forward (logZ) — round-1 proven version ----------------
__global__ __launch_bounds__(64) void crf_logz(const float* __restrict__ emis,
                                               const float* __restrict__ trans,
                                               const float* __restrict__ emisb,
                                               const float* __restrict__ transb,
                                               const float* __restrict__ mask,
                                               float* __restrict__ outLogZ) {
  const int crf = blockIdx.x >> 5, b = blockIdx.x & 31;
  const int NTc = crf ? 5 : 16;
  const float* __restrict__ E = crf ? emisb : emis;
  const float* __restrict__ T = crf ? transb : trans;
  const int lane = threadIdx.x;
  const int j = lane >> 2, p = lane & 3;
  const bool jv = (j < NTc);
  float Tc[4];
#pragma unroll
  for (int ii = 0; ii < 4; ++ii) {
    int i = p * 4 + ii;
    Tc[ii] = (jv && i < NTc) ? T[i * NTc + j] : -1e30f;
  }
  __shared__ float as_[16];
  if (lane < 16) as_[lane] = -1e30f;
  float alpha = 0.f;
  __syncthreads();
  if (jv && p == 0) {
    alpha = T[1 * NTc + j] + E[(size_t)(b << 10) * NTc + j];
    as_[j] = alpha;
  }
  __syncthreads();
  for (int t = 1; t < S_LEN; ++t) {
    float m_t = mask[(b << 10) + t];
    float v[4];
#pragma unroll
    for (int ii = 0; ii < 4; ++ii) {
      int i = p * 4 + ii;
      v[ii] = (jv && i < NTc) ? (as_[i] + Tc[ii]) : -1e30f;
    }
    float mx = fmaxf(fmaxf(v[0], v[1]), fmaxf(v[2], v[3]));
    mx = fmaxf(mx, __shfl_xor(mx, 1, 4));
    mx = fmaxf(mx, __shfl_xor(mx, 2, 4));
    float ssum = __expf(v[0] - mx) + __expf(v[1] - mx) + __expf(v[2] - mx) + __expf(v[3] - mx);
    ssum += __shfl_xor(ssum, 1, 4);
    ssum += __shfl_xor(ssum, 2, 4);
    if (jv && p == 0) {
      float e_tj = E[((size_t)(b << 10) + t) * NTc + j];
      float newv = e_tj + mx + __logf(ssum);
      alpha = (m_t > 0.5f) ? newv : alpha;
    }
    __syncthreads();
    if (jv && p == 0) as_[j] = alpha;
    __syncthreads();
  }
  if (lane == 0) {
    float mx = -1e30f;
    for (int jjx = 0; jjx < NTc; ++jjx) mx = fmaxf(mx, as_[jjx] + T[jjx * NTc + 2]);
    float ssum = 0.f;
    for (int jjx = 0; jjx < NTc; ++jjx) ssum += __expf(as_[jjx] + T[jjx * NTc + 2] - mx);
    outLogZ[crf * 32 + b] = mx + __logf(ssum);
  }
}

// ---------------- CRF gold score ----------------
__global__ __launch_bounds__(64) void crf_score(const float* __restrict__ emis,
                                                const float* __restrict__ trans,
                                                const float* __restrict__ emisb,
                                                const float* __restrict__ transb,
                                                const float* __restrict__ mask,
                                                const int* __restrict__ tags,
                                                const int* __restrict__ tagsb,
                                                float* __restrict__ outScore) {
  const int crf = blockIdx.x >> 5, b = blockIdx.x & 31;
  const int NTc = crf ? 5 : 16;
  const float* __restrict__ E = crf ? emisb : emis;
  const float* __restrict__ T = crf ? transb : trans;
  const int* __restrict__ tg = (crf ? tagsb : tags) + (b << 10);
  const float* __restrict__ mk = mask + (b << 10);
  const int lane = threadIdx.x;
  float s = 0.f, cnt = 0.f;
  for (int t = lane; t < S_LEN; t += 64) {
    float m = mk[t];
    cnt += m;
    if (t >= 1 && m > 0.5f)
      s += E[((size_t)(b << 10) + t) * NTc + tg[t]] + T[tg[t - 1] * NTc + tg[t]];
  }
#pragma unroll
  for (int off = 32; off >= 1; off >>= 1) {
    s += __shfl_down(s, off);
    cnt += __shfl_down(cnt, off);
  }
  if (lane == 0) {
    int L = (int)(cnt + 0.5f);
    int t0 = tg[0];
    float tot = T[1 * NTc + t0] + E[(size_t)(b << 10) * NTc + t0] + s + T[tg[L - 1] * NTc + 2];
    outScore[crf * 32 + b] = tot;
  }
}

__global__ void finalk(const float* __restrict__ logZ, const float* __restrict__ score,
                       float* __restrict__ out) {
  int j = threadIdx.x;
  if (j < 2) {
    float a = 0.f;
    for (int b = 0; b < 32; ++b) a += logZ[j * 32 + b] - score[j * 32 + b];
    out[j] = a;
  }
}

extern "C" void kernel_launch(void* const* d_in, const int* in_sizes, int n_in,
                              void* d_out, int out_size, void* d_ws, size_t ws_size,
                              hipStream_t stream) {
  const float* x       = (const float*)d_in[0];
  const float* xbin    = (const float*)d_in[1];
  const float* mask    = (const float*)d_in[2];
  const int*   tags    = (const int*)d_in[3];
  const int*   tagsb   = (const int*)d_in[4];
  const float* trans   = (const float*)d_in[5];
  const float* transb  = (const float*)d_in[6];
  const float* w2f_ih  = (const float*)d_in[7];
  const float* w2f_hh  = (const float*)d_in[8];
  const float* b2f_ih  = (const float*)d_in[9];
  const float* b2f_hh  = (const float*)d_in[10];
  const float* w2b_ih  = (const float*)d_in[11];
  const float* w2b_hh  = (const float*)d_in[12];
  const float* b2b_ih  = (const float*)d_in[13];
  const float* b2b_hh  = (const float*)d_in[14];
  const float* w_bin   = (const float*)d_in[15];
  const float* bb_bin  = (const float*)d_in[16];
  const float* w1f_ih  = (const float*)d_in[17];
  const float* w1f_hh  = (const float*)d_in[18];
  const float* b1f_ih  = (const float*)d_in[19];
  const float* b1f_hh  = (const float*)d_in[20];
  const float* w1b_ih  = (const float*)d_in[21];
  const float* w1b_hh  = (const float*)d_in[22];
  const float* b1b_ih  = (const float*)d_in[23];
  const float* b1b_hh  = (const float*)d_in[24];
  const float* w_tag   = (const float*)d_in[25];
  const float* b_tag   = (const float*)d_in[26];
  const float* h0_bin  = (const float*)d_in[27];
  const float* c0_bin  = (const float*)d_in[28];
  const float* h0_main = (const float*)d_in[29];
  const float* c0_main = (const float*)d_in[30];

  char* ws = (char*)d_ws;
  char* P4    = ws;                                   // 4u x 64MiB = 256MiB
  f16* hid4   = (f16*)(ws + 268435456);               // 64MiB
  char* Wq4   = ws + 335544320;                       // 4 x 262144 = 1MiB
  float* fsc4 = (float*)(ws + 336592896);             // 4096 f32
  f16* wtag   = (f16*)(ws + 336609280);               // 16384 f16
  f16* wbin   = (f16*)(ws + 336642048);               // 2560 f16
  float* emis  = (float*)(ws + 336647168);            // 32768*16 f32
  float* emisb = (float*)(ws + 338744320);            // 32768*5 f32
  float* logZ  = (float*)(ws + 339399680);            // 64 f32
  float* score = (float*)(ws + 339399936);            // 64 f32

  // weight preps
  quant_whh<<<256, 256, 0, stream>>>(w1f_hh, Wq4 + 0 * 262144, fsc4 + 0 * 1024);
  quant_whh<<<256, 256, 0, stream>>>(w1b_hh, Wq4 + 1 * 262144, fsc4 + 1 * 1024);
  quant_whh<<<256, 256, 0, stream>>>(w2f_hh, Wq4 + 2 * 262144, fsc4 + 2 * 1024);
  quant_whh<<<256, 256, 0, stream>>>(w2b_hh, Wq4 + 3 * 262144, fsc4 + 3 * 1024);
  cvt_f32_f16<<<16, 256, 0, stream>>>(w_tag, wtag, 4096);
  cvt_f32_f16<<<3, 256, 0, stream>>>(w_bin, wbin, 640);

  // input projections (log2e-scaled, P4 planes): units 0..3 = main_f, main_b, bin_f, bin_b
  dim3 gg(4, 256);
  proj_gemm<<<gg, 256, 0, stream>>>(x, w1f_ih, b1f_ih, b1f_hh, P4 + (size_t)0 * 67108864, 512);
  proj_gemm<<<gg, 256, 0, stream>>>(x, w1b_ih, b1b_ih, b1b_hh, P4 + (size_t)1 * 67108864, 512);
  proj_gemm<<<gg, 256, 0, stream>>>(xbin, w2f_ih, b2f_ih, b2f_hh, P4 + (size_t)2 * 67108864, 1536);
  proj_gemm<<<gg, 256, 0, stream>>>(xbin, w2b_ih, b2b_ih, b2b_hh, P4 + (size_t)3 * 67108864, 1536);

  lstm_rec3<<<16, 512, 0, stream>>>(Wq4, fsc4, P4, h0_main, c0_main, h0_bin, c0_bin, hid4);
  emis_kernel<<<2048, 256, 0, stream>>>(hid4, wtag, b_tag, wbin, bb_bin, emis, emisb);
  crf_logz<<<64, 64, 0, stream>>>(emis, trans, emisb, transb, mask, logZ);
  crf_score<<<64, 64, 0, stream>>>(emis, trans, emisb, transb, mask, tags, tagsb, score);
  finalk<<<1, 64, 0, stream>>>(logZ, score, (float*)d_out);
}

// Round 6
// 2334.564 us; speedup vs baseline: 1.8313x; 1.2758x over previous
//
#include <hip/hip_runtime.h>

typedef _Float16 f16;
typedef _Float16 f16x2 __attribute__((ext_vector_type(2)));
typedef _Float16 f16x4 __attribute__((ext_vector_type(4)));
typedef _Float16 f16x8 __attribute__((ext_vector_type(8)));
typedef float f32x4 __attribute__((ext_vector_type(4)));
typedef int iv4 __attribute__((ext_vector_type(4)));

#define S_LEN 1024
#define BATCH 32
#define HID 256
#define L2E 1.4426950408889634f
#define L2E2 2.8853900817779268f

#if __has_builtin(__builtin_amdgcn_fdot2)
#define FDOT2(a, b, c) __builtin_amdgcn_fdot2((a), (b), (c), false)
#else
static __device__ __forceinline__ float FDOT2(f16x2 a, f16x2 b, float c) {
  return c + (float)a[0] * (float)b[0] + (float)a[1] * (float)b[1];
}
#endif

__device__ __forceinline__ float EXP2(float x) {
#if __has_builtin(__builtin_amdgcn_exp2f)
  return __builtin_amdgcn_exp2f(x);
#else
  return exp2f(x);
#endif
}
__device__ __forceinline__ float RCP(float x) {
#if __has_builtin(__builtin_amdgcn_rcpf)
  return __builtin_amdgcn_rcpf(x);
#else
  return 1.0f / x;
#endif
}

// barrier that waits LDS only (no vmcnt drain of hid4 stores / P prefetch)
#define WG_BARRIER()                                                  \
  do {                                                                \
    __builtin_amdgcn_sched_barrier(0);                                \
    asm volatile("s_waitcnt lgkmcnt(0)\n\ts_barrier" ::: "memory");   \
    __builtin_amdgcn_sched_barrier(0);                                \
  } while (0)

__device__ __forceinline__ float dot8(f16x8 w, f16x8 h, float acc) {
  f16x2 a, b;
  a[0] = w[0]; a[1] = w[1]; b[0] = h[0]; b[1] = h[1]; acc = FDOT2(a, b, acc);
  a[0] = w[2]; a[1] = w[3]; b[0] = h[2]; b[1] = h[3]; acc = FDOT2(a, b, acc);
  a[0] = w[4]; a[1] = w[5]; b[0] = h[4]; b[1] = h[5]; acc = FDOT2(a, b, acc);
  a[0] = w[6]; a[1] = w[7]; b[0] = h[6]; b[1] = h[7]; acc = FDOT2(a, b, acc);
  return acc;
}

// ---------------- f32 -> f16 convert (plain) ----------------
__global__ void cvt_f32_f16(const float* __restrict__ src, f16* __restrict__ dst, int n4) {
  int i = blockIdx.x * 256 + threadIdx.x;
  if (i < n4) {
    float4 v = ((const float4*)src)[i];
    f16x4 h;
    h[0] = (f16)v.x; h[1] = (f16)v.y; h[2] = (f16)v.z; h[3] = (f16)v.w;
    ((f16x4*)dst)[i] = h;
  }
}

// ---------------- w_ih f32 -> f16, log2e row-scaled ----------------
__global__ void cvt_wih(const float* __restrict__ src, f16* __restrict__ dst, int K, int total8) {
  int i = blockIdx.x * 256 + threadIdx.x;
  if (i < total8) {
    int row = (int)(((long long)i * 8) / K);
    float sc = (row >= 512 && row < 768) ? L2E2 : L2E;
    const float* s = src + (size_t)i * 8;
    float4 a = *(const float4*)s;
    float4 b = *(const float4*)(s + 4);
    f16x8 h;
    h[0] = (f16)(a.x * sc); h[1] = (f16)(a.y * sc); h[2] = (f16)(a.z * sc); h[3] = (f16)(a.w * sc);
    h[4] = (f16)(b.x * sc); h[5] = (f16)(b.y * sc); h[6] = (f16)(b.z * sc); h[7] = (f16)(b.w * sc);
    *(f16x8*)(dst + (size_t)i * 8) = h;
  }
}

// ---------------- whh f32 -> i8 per-row symmetric quant, log2e pre-scaled ----------------
__global__ __launch_bounds__(256) void quant_whh(const float* __restrict__ src,
                                                 char* __restrict__ dstq,
                                                 float* __restrict__ fsc) {
  const int row = blockIdx.x * 4 + (threadIdx.x >> 6);
  const int lane = threadIdx.x & 63;
  const float sc = (row >= 512 && row < 768) ? L2E2 : L2E;
  float4 v = *(const float4*)(src + (size_t)row * 256 + lane * 4);
  float w0 = v.x * sc, w1 = v.y * sc, w2 = v.z * sc, w3 = v.w * sc;
  float mx = fmaxf(fmaxf(fabsf(w0), fabsf(w1)), fmaxf(fabsf(w2), fabsf(w3)));
#pragma unroll
  for (int off = 1; off < 64; off <<= 1) mx = fmaxf(mx, __shfl_xor(mx, off));
  mx = fmaxf(mx, 1e-20f);
  float inv = 127.0f / mx;
  int q0 = (int)rintf(w0 * inv), q1 = (int)rintf(w1 * inv);
  int q2 = (int)rintf(w2 * inv), q3 = (int)rintf(w3 * inv);
  int pk = (q0 & 0xff) | ((q1 & 0xff) << 8) | ((q2 & 0xff) << 16) | ((q3 & 0xff) << 24);
  ((int*)(dstq + (size_t)row * 256))[lane] = pk;
  if (lane == 0) fsc[row] = mx / 16129.0f;
}

// ---------------- input-projection GEMM -> P4 planes ----------------
// (structure proven in round 5; B now pre-converted f16, staging is load+store only)
__global__ __launch_bounds__(256) void proj_gemm(const float* __restrict__ A,
                                                 const f16* __restrict__ W16,
                                                 const float* __restrict__ bih,
                                                 const float* __restrict__ bhh,
                                                 char* __restrict__ Pu, int K) {
  __shared__ __align__(16) char smem[65536];
  f16* As = (f16*)smem;            // [128][64]
  f16* Bs = (f16*)(smem + 16384);  // [256][64]
  const int v = blockIdx.x;
  const int bm = blockIdx.y;
  const int bgrp = bm >> 5, t0 = (bm & 31) * 32;
  const int b0 = bgrp * 4, c = bgrp >> 1, lkb = bgrp & 1;
  const float sc = (v == 2) ? L2E2 : L2E;
  const int tid = threadIdx.x;
  const int lane = tid & 63, wid = tid >> 6;
  const int wm = wid >> 1, wn = wid & 1;
  const int lr = lane & 15, lk = lane >> 4;

  f32x4 acc[4][8];
#pragma unroll
  for (int i = 0; i < 4; ++i)
#pragma unroll
    for (int n = 0; n < 8; ++n) acc[i][n] = (f32x4){0.f, 0.f, 0.f, 0.f};

  for (int k0 = 0; k0 < K; k0 += 64) {
    // stage A (f32 -> f16 converts): 1024 slots, 4/thread
#pragma unroll
    for (int s = 0; s < 4; ++s) {
      int slot = s * 256 + tid;
      int row = slot >> 3, seg = slot & 7;
      size_t arow = (size_t)(b0 + (row >> 5)) * 1024 + t0 + (row & 31);
      const float* ga = A + arow * K + (k0 + seg * 8);
      float4 v0 = *(const float4*)ga;
      float4 v1 = *(const float4*)(ga + 4);
      f16x8 h;
      h[0] = (f16)v0.x; h[1] = (f16)v0.y; h[2] = (f16)v0.z; h[3] = (f16)v0.w;
      h[4] = (f16)v1.x; h[5] = (f16)v1.y; h[6] = (f16)v1.z; h[7] = (f16)v1.w;
      *(f16x8*)(&As[slot * 8]) = h;
    }
    // stage B (pre-converted f16): 2048 slots, 8/thread, pure 16B copy
#pragma unroll
    for (int s = 0; s < 8; ++s) {
      int slot = s * 256 + tid;
      int row = slot >> 3, seg = slot & 7;
      const f16* gb = W16 + (size_t)(v * 256 + row) * K + (k0 + seg * 8);
      *(f16x8*)(&Bs[slot * 8]) = *(const f16x8*)gb;
    }
    __syncthreads();
#pragma unroll
    for (int kk = 0; kk < 64; kk += 32) {
      f16x8 af[4], bf[8];
#pragma unroll
      for (int mi = 0; mi < 4; ++mi)
        af[mi] = *(const f16x8*)(&As[(wm * 64 + mi * 16 + lr) * 64 + kk + lk * 8]);
#pragma unroll
      for (int ni = 0; ni < 8; ++ni)
        bf[ni] = *(const f16x8*)(&Bs[(wn * 128 + ni * 16 + lr) * 64 + kk + lk * 8]);
#pragma unroll
      for (int mi = 0; mi < 4; ++mi)
#pragma unroll
        for (int ni = 0; ni < 8; ++ni)
          acc[mi][ni] = __builtin_amdgcn_mfma_f32_16x16x32_f16(af[mi], bf[ni], acc[mi][ni], 0, 0, 0);
    }
    __syncthreads();
  }

  // epilogue: acc -> LDS (swizzled) -> coalesced 8B stores (round-5 proven)
  float biasv[8];
#pragma unroll
  for (int ni = 0; ni < 8; ++ni) {
    int n = v * 256 + wn * 128 + ni * 16 + lr;
    biasv[ni] = (bih[n] + bhh[n]) * sc;
  }
#pragma unroll
  for (int mi = 0; mi < 4; ++mi) {
#pragma unroll
    for (int ni = 0; ni < 8; ++ni) {
      int col = wn * 128 + ni * 16 + lr;
      int wc = col >> 5, jc = (col >> 4) & 1, lc = col & 15;
#pragma unroll
      for (int rr = 0; rr < 4; ++rr) {
        int row = wm * 64 + mi * 16 + lk * 4 + rr;
        int bsub = row >> 5, t_loc = row & 31;
        int unit = t_loc * 256 + wc * 32 + jc * 16 + lc;
        int off = (unit * 8 + bsub * 2) ^ ((t_loc & 7) << 4);
        *(f16*)(smem + off) = (f16)(acc[mi][ni][rr] + biasv[ni]);
      }
    }
  }
  __syncthreads();
  char* Pv = Pu + ((size_t)v << 24);
#pragma unroll
  for (int k = 0; k < 32; ++k) {
    int uid = k * 256 + tid;
    int t_loc = uid >> 8, sub = uid & 255;
    int off = (uid * 8) ^ ((t_loc & 7) << 4);
    unsigned long long val = *(const unsigned long long*)(smem + off);
    int wq = sub >> 5, jq = (sub >> 4) & 1, lq = sub & 15;
    size_t didx = (((size_t)((t0 + t_loc) * 4 + c) * 512) + wq * 64 + jq * 32 + lkb * 16 + lq) << 3;
    *(unsigned long long*)(Pv + didx) = val;
  }
}

// ---------------- LSTM recurrence: 32 WGs = (unit, 4-batch-eighth), i8 MFMA ----------------
__global__ __attribute__((amdgpu_flat_work_group_size(512, 512), amdgpu_waves_per_eu(2, 2)))
void lstm_rec4(const char* __restrict__ Wq4,
               const float* __restrict__ fsc4,
               const char* __restrict__ P4,
               const float* __restrict__ h0m,
               const float* __restrict__ c0m,
               const float* __restrict__ h0b,
               const float* __restrict__ c0b,
               f16* __restrict__ hid4) {
  const int wg = blockIdx.x;
  const int u = wg >> 3, c8 = wg & 7;
  const int dir = u & 1;
  const int tid = threadIdx.x;
  const int l = tid & 63, w = tid >> 6;
  const int lr = l & 15, lk = l >> 4;
  const int jj = lk >> 1, selb = lk & 1;
  const int r4 = lr & 3;
  const int swzA = (r4 << 4) | ((r4 & 1) << 6);
  const int j = w * 32 + jj * 16 + lr;  // hidden unit owned by this lane
  const int cq = c8 >> 1;

  __shared__ __align__(16) char hbuf[2][1024];  // [4 batch rows][256 k] i8, swizzled

  // ---- weights: 32 x iv4 = 128 regs ----
  iv4 Bf[4][8];
  const char* wb = Wq4 + ((size_t)u << 18);
#pragma unroll
  for (int nt = 0; nt < 8; ++nt) {
    int n = (nt >> 1) * 256 + w * 32 + ((nt & 1) << 4) + lr;
#pragma unroll
    for (int ks = 0; ks < 4; ++ks)
      Bf[ks][nt] = *(const iv4*)(wb + (size_t)n * 256 + ks * 64 + lk * 16);
  }
  float fv[4], fv4[4];
#pragma unroll
  for (int v = 0; v < 4; ++v) {
    fv[v] = fsc4[u * 1024 + v * 256 + j];
    fv4[v] = fv[v] * 4.f;
  }

  // ---- init c / h0 (h0 quantized at scale 127/4, step-0 uses fv4) ----
  const float* h0 = (u < 2 ? h0m : h0b) + (size_t)dir * BATCH * HID;
  const float* c0 = (u < 2 ? c0m : c0b) + (size_t)dir * BATCH * HID;
  float cst[2];
#pragma unroll
  for (int i = 0; i < 2; ++i) {
    int bloc = selb * 2 + i;
    int b = c8 * 4 + bloc;
    cst[i] = c0[b * HID + j];
    float hv = h0[b * HID + j] * 31.75f;
    int hq = (int)rintf(hv);
    hq = hq > 127 ? 127 : (hq < -127 ? -127 : hq);
    int swzW = (bloc << 4) | ((bloc & 1) << 6);
    hbuf[0][bloc * 256 + (j ^ swzW)] = (char)hq;
  }

  // ---- P preload for s=0 ----
  const char* Pc = P4 + ((size_t)u << 26);
  const size_t soff = (size_t)((w * 64 + jj * 32 + ((c8 & 1) << 4) + lr) * 8 + selb * 4);
  f16x2 Pa[4], Pb[4];
  {
    int t0 = dir ? (S_LEN - 1) : 0;
    size_t tb = ((size_t)((t0 << 2) + cq) << 12) + soff;
#pragma unroll
    for (int v = 0; v < 4; ++v) Pa[v] = *(const f16x2*)(Pc + ((size_t)v << 24) + tb);
  }
  WG_BARRIER();

#define LSTM_STEP(S_, SP_, PC_, PN_, FV_)                                                   \
  {                                                                                         \
    const int t = dir ? (S_LEN - 1 - (S_)) : (S_);                                          \
    {                                                                                       \
      int s2 = ((S_) + 1 < S_LEN) ? (S_) + 1 : (S_);                                        \
      int t2 = dir ? (S_LEN - 1 - s2) : s2;                                                 \
      size_t tb = ((size_t)((t2 << 2) + cq) << 12) + soff;                                  \
      _Pragma("unroll") for (int v = 0; v < 4; ++v)                                         \
          PN_[v] = *(const f16x2*)(Pc + ((size_t)v << 24) + tb);                            \
    }                                                                                       \
    iv4 ia[8];                                                                              \
    _Pragma("unroll") for (int nt = 0; nt < 8; ++nt) ia[nt] = (iv4){0, 0, 0, 0};            \
    const char* hb = hbuf[SP_];                                                             \
    _Pragma("unroll") for (int ks = 0; ks < 4; ++ks) {                                      \
      iv4 Af = *(const iv4*)(hb + r4 * 256 + ((ks * 64 + lk * 16) ^ swzA));                 \
      _Pragma("unroll") for (int nt = 0; nt < 8; ++nt)                                      \
          ia[nt] = __builtin_amdgcn_mfma_i32_16x16x64_i8(Af, Bf[ks][nt], ia[nt], 0, 0, 0);  \
    }                                                                                       \
    float hh2[2];                                                                           \
    _Pragma("unroll") for (int i = 0; i < 2; ++i) {                                         \
      float z[4];                                                                           \
      _Pragma("unroll") for (int v = 0; v < 4; ++v) {                                       \
        int e0 = selb ? ia[v * 2][2 + i] : ia[v * 2][i];                                    \
        int e1 = selb ? ia[v * 2 + 1][2 + i] : ia[v * 2 + 1][i];                            \
        int iz = jj ? e1 : e0;                                                              \
        z[v] = (float)PC_[v][i] + FV_[v] * (float)iz;                                       \
      }                                                                                     \
      float zi = z[0], zf = z[1], zg = z[2], zo = z[3];                                     \
      float ei = EXP2(-zi), ef = EXP2(-zf), eg = EXP2(-zg), eo = EXP2(-zo);                 \
      float di = 1.f + ei, df = 1.f + ef, dg = 1.f + eg, dof = 1.f + eo;                    \
      float r1 = RCP(di * df);                                                              \
      float si = r1 * df, sf = r1 * di;                                                     \
      float r2 = RCP(dg * dof);                                                             \
      float tg = 2.f * (r2 * dof) - 1.f, so = r2 * dg;                                      \
      float cc = sf * cst[i] + si * tg;                                                     \
      cst[i] = cc;                                                                          \
      float ec = EXP2(-L2E2 * cc);                                                          \
      float th = 2.f * RCP(1.f + ec) - 1.f;                                                 \
      hh2[i] = so * th;                                                                     \
    }                                                                                       \
    _Pragma("unroll") for (int i = 0; i < 2; ++i) {                                         \
      int bloc = selb * 2 + i;                                                              \
      int swzW = (bloc << 4) | ((bloc & 1) << 6);                                           \
      int hq = (int)rintf(hh2[i] * 127.f);                                                  \
      hbuf[SP_ ^ 1][bloc * 256 + (j ^ swzW)] = (char)hq;                                    \
      int b = c8 * 4 + bloc;                                                                \
      hid4[((size_t)b << 20) + ((size_t)t << 10) + (u << 8) + j] = (f16)hh2[i];             \
    }                                                                                       \
    WG_BARRIER();                                                                           \
  }

  LSTM_STEP(0, 0, Pa, Pb, fv4);
  for (int s = 1; s <= 1021; s += 2) {
    LSTM_STEP(s, 1, Pb, Pa, fv);
    LSTM_STEP(s + 1, 0, Pa, Pb, fv);
  }
  LSTM_STEP(1023, 1, Pb, Pa, fv);
#undef LSTM_STEP
}

// ---------------- emissions ----------------
__global__ __launch_bounds__(256) void emis_kernel(const f16* __restrict__ hid4,
                                                   const f16* __restrict__ wtag,
                                                   const float* __restrict__ btag,
                                                   const f16* __restrict__ wbin,
                                                   const float* __restrict__ bbin,
                                                   float* __restrict__ emis,
                                                   float* __restrict__ emisb) {
  const int tid = threadIdx.x;
  const int rl = tid >> 4, n = tid & 15;
  const size_t row = (size_t)blockIdx.x * 16 + rl;
  const f16x8* hv = (const f16x8*)(hid4 + row * 1024);
  const f16x8* wv = (const f16x8*)(wtag + n * 1024);
  float acc = btag[n];
#pragma unroll 8
  for (int kc = 0; kc < 128; ++kc) acc = dot8(wv[kc], hv[kc], acc);
  emis[row * 16 + n] = acc;
  if (n < 5) {
    const f16x8* hv2 = (const f16x8*)(hid4 + row * 1024 + 512);
    const f16x8* wv2 = (const f16x8*)(wbin + (size_t)n * 512);
    float a2 = bbin[n];
#pragma unroll 8
    for (int kc = 0; kc < 64; ++kc) a2 = dot8(wv2[kc], hv2[kc], a2);
    emisb[row * 5 + n] = a2;
  }
}

// ---------------- CRF forward (logZ): proven structure + dbuf as_ + E/mask prefetch ----------------
__global__ __launch_bounds__(64) void crf_logz(const float* __restrict__ emis,
                                               const float* __restrict__ trans,
                                               const float* __restrict__ emisb,
                                               const float* __restrict__ transb,
                                               const float* __restrict__ mask,
                                               float* __restrict__ outLogZ) {
  const int crf = blockIdx.x >> 5, b = blockIdx.x & 31;
  const int NTc = crf ? 5 : 16;
  const float* __restrict__ E = crf ? emisb : emis;
  const float* __restrict__ T = crf ? transb : trans;
  const int lane = threadIdx.x;
  const int jn = lane >> 2, p = lane & 3;
  const bool jv = (jn < NTc);
  const int jc = jv ? jn : 0;
  float Tc[4];
#pragma unroll
  for (int ii = 0; ii < 4; ++ii) {
    int i = p * 4 + ii;
    Tc[ii] = (jv && i < NTc) ? T[i * NTc + jn] : -1e30f;
  }
  __shared__ float as_[2][16];
  if (lane < 16) { as_[0][lane] = -1e30f; as_[1][lane] = -1e30f; }
  __syncthreads();
  float alpha = 0.f;
  if (jv && p == 0) {
    alpha = T[1 * NTc + jn] + E[(size_t)(b << 10) * NTc + jn];  // SOS=1, t=0
    as_[0][jn] = alpha;
  }
  __syncthreads();
  int cur = 0;
  const size_t ebase = (size_t)(b << 10) * NTc + jc;
  const int mbase = b << 10;
#define LDE(tt) E[ebase + (size_t)(tt)*NTc]
#define LDM(tt) mask[mbase + (tt)]

  auto step = [&](float e_tj, float m_t) {
    float v0 = (jv && (p * 4 + 0) < NTc) ? (as_[cur][p * 4 + 0] + Tc[0]) : -1e30f;
    float v1 = (jv && (p * 4 + 1) < NTc) ? (as_[cur][p * 4 + 1] + Tc[1]) : -1e30f;
    float v2 = (jv && (p * 4 + 2) < NTc) ? (as_[cur][p * 4 + 2] + Tc[2]) : -1e30f;
    float v3 = (jv && (p * 4 + 3) < NTc) ? (as_[cur][p * 4 + 3] + Tc[3]) : -1e30f;
    float mx = fmaxf(fmaxf(v0, v1), fmaxf(v2, v3));
    mx = fmaxf(mx, __shfl_xor(mx, 1, 4));
    mx = fmaxf(mx, __shfl_xor(mx, 2, 4));
    float ss = __expf(v0 - mx) + __expf(v1 - mx) + __expf(v2 - mx) + __expf(v3 - mx);
    ss += __shfl_xor(ss, 1, 4);
    ss += __shfl_xor(ss, 2, 4);
    if (jv && p == 0) {
      float newv = e_tj + mx + __logf(ss);
      alpha = (m_t > 0.5f) ? newv : alpha;
      as_[cur ^ 1][jn] = alpha;
    }
    __syncthreads();
    cur ^= 1;
  };

  float eb[4], mb[4];
#pragma unroll
  for (int k = 0; k < 4; ++k) { eb[k] = LDE(1 + k); mb[k] = LDM(1 + k); }
  for (int t = 1; t <= 1017; t += 4) {
    float en[4], mn[4];
#pragma unroll
    for (int k = 0; k < 4; ++k) {
      int ix = t + 4 + k;
      ix = ix > 1023 ? 1023 : ix;
      en[k] = LDE(ix);
      mn[k] = LDM(ix);
    }
    step(eb[0], mb[0]); step(eb[1], mb[1]); step(eb[2], mb[2]); step(eb[3], mb[3]);
#pragma unroll
    for (int k = 0; k < 4; ++k) { eb[k] = en[k]; mb[k] = mn[k]; }
  }
  // t = 1021..1023
  step(eb[0], mb[0]); step(eb[1], mb[1]); step(eb[2], mb[2]);
#undef LDE
#undef LDM

  if (lane == 0) {
    float mx = -1e30f;
    for (int jjx = 0; jjx < NTc; ++jjx) mx = fmaxf(mx, as_[cur][jjx] + T[jjx * NTc + 2]);  // EOS=2
    float ss = 0.f;
    for (int jjx = 0; jjx < NTc; ++jjx) ss += __expf(as_[cur][jjx] + T[jjx * NTc + 2] - mx);
    outLogZ[crf * 32 + b] = mx + __logf(ss);
  }
}

// ---------------- CRF gold score ----------------
__global__ __launch_bounds__(64) void crf_score(const float* __restrict__ emis,
                                                const float* __restrict__ trans,
                                                const float* __restrict__ emisb,
                                                const float* __restrict__ transb,
                                                const float* __restrict__ mask,
                                                const int* __restrict__ tags,
                                                const int* __restrict__ tagsb,
                                                float* __restrict__ outScore) {
  const int crf = blockIdx.x >> 5, b = blockIdx.x & 31;
  const int NTc = crf ? 5 : 16;
  const float* __restrict__ E = crf ? emisb : emis;
  const float* __restrict__ T = crf ? transb : trans;
  const int* __restrict__ tg = (crf ? tagsb : tags) + (b << 10);
  const float* __restrict__ mk = mask + (b << 10);
  const int lane = threadIdx.x;
  float s = 0.f, cnt = 0.f;
  for (int t = lane; t < S_LEN; t += 64) {
    float m = mk[t];
    cnt += m;
    if (t >= 1 && m > 0.5f)
      s += E[((size_t)(b << 10) + t) * NTc + tg[t]] + T[tg[t - 1] * NTc + tg[t]];
  }
#pragma unroll
  for (int off = 32; off >= 1; off >>= 1) {
    s += __shfl_down(s, off);
    cnt += __shfl_down(cnt, off);
  }
  if (lane == 0) {
    int L = (int)(cnt + 0.5f);
    int t0 = tg[0];
    float tot = T[1 * NTc + t0] + E[(size_t)(b << 10) * NTc + t0] + s + T[tg[L - 1] * NTc + 2];
    outScore[crf * 32 + b] = tot;
  }
}

__global__ void finalk(const float* __restrict__ logZ, const float* __restrict__ score,
                       float* __restrict__ out) {
  int j = threadIdx.x;
  if (j < 2) {
    float a = 0.f;
    for (int b = 0; b < 32; ++b) a += logZ[j * 32 + b] - score[j * 32 + b];
    out[j] = a;
  }
}

extern "C" void kernel_launch(void* const* d_in, const int* in_sizes, int n_in,
                              void* d_out, int out_size, void* d_ws, size_t ws_size,
                              hipStream_t stream) {
  const float* x       = (const float*)d_in[0];
  const float* xbin    = (const float*)d_in[1];
  const float* mask    = (const float*)d_in[2];
  const int*   tags    = (const int*)d_in[3];
  const int*   tagsb   = (const int*)d_in[4];
  const float* trans   = (const float*)d_in[5];
  const float* transb  = (const float*)d_in[6];
  const float* w2f_ih  = (const float*)d_in[7];
  const float* w2f_hh  = (const float*)d_in[8];
  const float* b2f_ih  = (const float*)d_in[9];
  const float* b2f_hh  = (const float*)d_in[10];
  const float* w2b_ih  = (const float*)d_in[11];
  const float* w2b_hh  = (const float*)d_in[12];
  const float* b2b_ih  = (const float*)d_in[13];
  const float* b2b_hh  = (const float*)d_in[14];
  const float* w_bin   = (const float*)d_in[15];
  const float* bb_bin  = (const float*)d_in[16];
  const float* w1f_ih  = (const float*)d_in[17];
  const float* w1f_hh  = (const float*)d_in[18];
  const float* b1f_ih  = (const float*)d_in[19];
  const float* b1f_hh  = (const float*)d_in[20];
  const float* w1b_ih  = (const float*)d_in[21];
  const float* w1b_hh  = (const float*)d_in[22];
  const float* b1b_ih  = (const float*)d_in[23];
  const float* b1b_hh  = (const float*)d_in[24];
  const float* w_tag   = (const float*)d_in[25];
  const float* b_tag   = (const float*)d_in[26];
  const float* h0_bin  = (const float*)d_in[27];
  const float* c0_bin  = (const float*)d_in[28];
  const float* h0_main = (const float*)d_in[29];
  const float* c0_main = (const float*)d_in[30];

  char* ws = (char*)d_ws;
  char* P4    = ws;                                   // 4u x 64MiB = 256MiB
  f16* hid4   = (f16*)(ws + 268435456);               // 64MiB
  char* Wq4   = ws + 335544320;                       // 1MiB
  float* fsc4 = (float*)(ws + 336592896);             // 16KB
  f16* wtag   = (f16*)(ws + 336609280);
  f16* wbin   = (f16*)(ws + 336642048);
  float* emis  = (float*)(ws + 336647168);            // 2MiB
  float* emisb = (float*)(ws + 338744320);
  float* logZ  = (float*)(ws + 339399680);
  float* score = (float*)(ws + 339399936);
  f16* w1f16 = (f16*)(ws + 340000768);                // 1MiB each (K=512)
  f16* w1b16 = (f16*)(ws + 341049344);
  f16* w2f16 = (f16*)(ws + 342097920);                // 3MiB each (K=1536)
  f16* w2b16 = (f16*)(ws + 345243648);                // ends ~348.4MB

  // weight preps
  quant_whh<<<256, 256, 0, stream>>>(w1f_hh, Wq4 + 0 * 262144, fsc4 + 0 * 1024);
  quant_whh<<<256, 256, 0, stream>>>(w1b_hh, Wq4 + 1 * 262144, fsc4 + 1 * 1024);
  quant_whh<<<256, 256, 0, stream>>>(w2f_hh, Wq4 + 2 * 262144, fsc4 + 2 * 1024);
  quant_whh<<<256, 256, 0, stream>>>(w2b_hh, Wq4 + 3 * 262144, fsc4 + 3 * 1024);
  cvt_f32_f16<<<16, 256, 0, stream>>>(w_tag, wtag, 4096);
  cvt_f32_f16<<<3, 256, 0, stream>>>(w_bin, wbin, 640);
  cvt_wih<<<256, 256, 0, stream>>>(w1f_ih, w1f16, 512, 65536);
  cvt_wih<<<256, 256, 0, stream>>>(w1b_ih, w1b16, 512, 65536);
  cvt_wih<<<768, 256, 0, stream>>>(w2f_ih, w2f16, 1536, 196608);
  cvt_wih<<<768, 256, 0, stream>>>(w2b_ih, w2b16, 1536, 196608);

  // input projections: units 0..3 = main_f, main_b, bin_f, bin_b
  dim3 gg(4, 256);
  proj_gemm<<<gg, 256, 0, stream>>>(x, w1f16, b1f_ih, b1f_hh, P4 + (size_t)0 * 67108864, 512);
  proj_gemm<<<gg, 256, 0, stream>>>(x, w1b16, b1b_ih, b1b_hh, P4 + (size_t)1 * 67108864, 512);
  proj_gemm<<<gg, 256, 0, stream>>>(xbin, w2f16, b2f_ih, b2f_hh, P4 + (size_t)2 * 67108864, 1536);
  proj_gemm<<<gg, 256, 0, stream>>>(xbin, w2b16, b2b_ih, b2b_hh, P4 + (size_t)3 * 67108864, 1536);

  lstm_rec4<<<32, 512, 0, stream>>>(Wq4, fsc4, P4, h0_main, c0_main, h0_bin, c0_bin, hid4);
  emis_kernel<<<2048, 256, 0, stream>>>(hid4, wtag, b_tag, wbin, bb_bin, emis, emisb);
  crf_logz<<<64, 64, 0, stream>>>(emis, trans, emisb, transb, mask, logZ);
  crf_score<<<64, 64, 0, stream>>>(emis, trans, emisb, transb, mask, tags, tagsb, score);
  finalk<<<1, 64, 0, stream>>>(logZ, score, (float*)d_out);
}